// Round 1
// baseline (453.065 us; speedup 1.0000x reference)
//
#include <hip/hip_runtime.h>

// NeuralODE: x_{s+1} = x_s + (tanh(tanh(x W1 + b1) W2 + b2) W3 + b3) * dt_scale * 0.01
// BATCH=4096, STATE=64, HIDDEN=256, steps=200. Output [4096, steps+1, 64] fp32.
//
// Strategy: persistent blocks, 16 batch rows / block, 256 blocks (1/CU).
// Weights converted to bf16 [N][K] once (prep kernel into d_ws), then held in
// registers as MFMA B-fragments for all 200 steps. Activations round-trip
// through LDS in bf16. x state kept fp32 in LDS.

#define STATE_DIM 64
#define HIDDEN    256
#define BATCH     4096
#define TILE_M    16
#define NBLK      (BATCH / TILE_M)   // 256 blocks
#define XPITCH    72                 // 64 + 8 shorts: 2-way bank alias only
#define HPITCH    264                // 256 + 8 shorts

typedef short v8s __attribute__((ext_vector_type(8)));
typedef float v4f __attribute__((ext_vector_type(4)));

__device__ __forceinline__ unsigned short f2bf(float f) {
    unsigned u = __float_as_uint(f);
    u += 0x7fffu + ((u >> 16) & 1u);     // round-to-nearest-even
    return (unsigned short)(u >> 16);
}

__device__ __forceinline__ float fast_tanh(float x) {
    // tanh(x) = 1 - 2/(exp(2x)+1);  exp(2x) = exp2(x * 2*log2(e))
    float e = __builtin_amdgcn_exp2f(x * 2.8853900817779268f);
    return 1.0f - 2.0f * __builtin_amdgcn_rcpf(e + 1.0f);
}

// ---- prep: fp32 weights -> bf16, transposed to [N][K] for B-fragment loads ----
__global__ void prep_weights(const float* __restrict__ W1,
                             const float* __restrict__ W2,
                             const float* __restrict__ W3,
                             short* __restrict__ W1t,   // [256][64]
                             short* __restrict__ W2t,   // [256][256]
                             short* __restrict__ W3t) { // [64][256]
    int u = blockIdx.x * 256 + threadIdx.x;
    if (u < 65536) {                       // W2t[n][k] = W2[k][n]
        int n = u >> 8, k = u & 255;
        W2t[u] = (short)f2bf(W2[k * 256 + n]);
    }
    int v = u - 65536;
    if (v >= 0 && v < 16384) {             // W1t[n][k] = W1[k][n]
        int n = v >> 6, k = v & 63;
        W1t[v] = (short)f2bf(W1[k * 256 + n]);
    }
    int t = u - (65536 + 16384);
    if (t >= 0 && t < 16384) {             // W3t[n][k] = W3[k][n]
        int n = t >> 8, k = t & 255;
        W3t[t] = (short)f2bf(W3[k * 64 + n]);
    }
}

// ---- main persistent kernel ----
__global__ __launch_bounds__(512, 2)
void ode_kernel(const float* __restrict__ x0,
                const float* __restrict__ b1,
                const float* __restrict__ b2,
                const float* __restrict__ b3,
                const float* __restrict__ dt_scale,
                const int*   __restrict__ stepsp,
                const short* __restrict__ W1t,
                const short* __restrict__ W2t,
                const short* __restrict__ W3t,
                float* __restrict__ out) {
    __shared__ float xs[TILE_M * STATE_DIM];   // fp32 state
    __shared__ short xb[TILE_M * XPITCH];      // bf16 state (MFMA A source)
    __shared__ short h1b[TILE_M * HPITCH];     // bf16 h1
    __shared__ short h2b[TILE_M * HPITCH];     // bf16 h2

    const int tid  = threadIdx.x;
    const int w    = tid >> 6;        // wave 0..7
    const int lane = tid & 63;
    const int ln   = lane & 15;       // row (A) / col (B,C) within tile
    const int q    = lane >> 4;       // quad 0..3
    const int blk  = blockIdx.x;
    const int nsteps = *stepsp;
    const float scale = dt_scale[0] * 0.01f;

    // ---- load weight B-fragments into registers ----
    // B-frag layout (16x16x32): lane holds B[k = 32*ks + 8*q + j][n = n0 + ln]
    v8s w1f[2][2], w2f[2][8], w3f[8];
    const int n0 = 32 * w;
    #pragma unroll
    for (int t = 0; t < 2; t++)
        #pragma unroll
        for (int s = 0; s < 2; s++)
            w1f[t][s] = *(const v8s*)(W1t + (n0 + 16 * t + ln) * 64 + 32 * s + 8 * q);
    #pragma unroll
    for (int t = 0; t < 2; t++)
        #pragma unroll
        for (int s = 0; s < 8; s++)
            w2f[t][s] = *(const v8s*)(W2t + (n0 + 16 * t + ln) * 256 + 32 * s + 8 * q);
    if (w < 4) {
        #pragma unroll
        for (int s = 0; s < 8; s++)
            w3f[s] = *(const v8s*)(W3t + (16 * w + ln) * 256 + 32 * s + 8 * q);
    }
    float b1r[2], b2r[2], b3r = 0.0f;
    #pragma unroll
    for (int t = 0; t < 2; t++) {
        b1r[t] = b1[n0 + 16 * t + ln];
        b2r[t] = b2[n0 + 16 * t + ln];
    }
    if (w < 4) b3r = b3[16 * w + ln];

    // ---- init x from x0 ----
    {
        int r = tid >> 5, c = (tid & 31) * 2;
        const float2 v = *(const float2*)(x0 + (size_t)(blk * TILE_M + r) * STATE_DIM + c);
        xs[r * STATE_DIM + c]     = v.x;
        xs[r * STATE_DIM + c + 1] = v.y;
        xb[r * XPITCH + c]     = (short)f2bf(v.x);
        xb[r * XPITCH + c + 1] = (short)f2bf(v.y);
    }
    __syncthreads();

    const size_t orow = (size_t)(nsteps + 1) * STATE_DIM;   // per-batch-row stride

    for (int s = 0; s <= nsteps; s++) {
        // ---- write trajectory sample s (coalesced float2/thread) ----
        {
            int r = tid >> 5, c = (tid & 31) * 2;
            float2 v;
            v.x = xs[r * STATE_DIM + c];
            v.y = xs[r * STATE_DIM + c + 1];
            *(float2*)(out + (size_t)(blk * TILE_M + r) * orow + (size_t)s * STATE_DIM + c) = v;
        }
        if (s == nsteps) break;

        // ---- layer 1: h1 = tanh(x @ W1 + b1), M=16 K=64 N=256 ----
        v4f acc0 = {0.f, 0.f, 0.f, 0.f}, acc1 = {0.f, 0.f, 0.f, 0.f};
        #pragma unroll
        for (int ks = 0; ks < 2; ks++) {
            v8s a = *(const v8s*)(xb + ln * XPITCH + 32 * ks + 8 * q);
            acc0 = __builtin_amdgcn_mfma_f32_16x16x32_bf16(a, w1f[0][ks], acc0, 0, 0, 0);
            acc1 = __builtin_amdgcn_mfma_f32_16x16x32_bf16(a, w1f[1][ks], acc1, 0, 0, 0);
        }
        #pragma unroll
        for (int i = 0; i < 4; i++) {
            int row = q * 4 + i;
            h1b[row * HPITCH + n0 + ln]      = (short)f2bf(fast_tanh(acc0[i] + b1r[0]));
            h1b[row * HPITCH + n0 + 16 + ln] = (short)f2bf(fast_tanh(acc1[i] + b1r[1]));
        }
        __syncthreads();

        // ---- layer 2: h2 = tanh(h1 @ W2 + b2), M=16 K=256 N=256 ----
        acc0 = (v4f){0.f, 0.f, 0.f, 0.f};
        acc1 = (v4f){0.f, 0.f, 0.f, 0.f};
        #pragma unroll
        for (int ks = 0; ks < 8; ks++) {
            v8s a = *(const v8s*)(h1b + ln * HPITCH + 32 * ks + 8 * q);
            acc0 = __builtin_amdgcn_mfma_f32_16x16x32_bf16(a, w2f[0][ks], acc0, 0, 0, 0);
            acc1 = __builtin_amdgcn_mfma_f32_16x16x32_bf16(a, w2f[1][ks], acc1, 0, 0, 0);
        }
        #pragma unroll
        for (int i = 0; i < 4; i++) {
            int row = q * 4 + i;
            h2b[row * HPITCH + n0 + ln]      = (short)f2bf(fast_tanh(acc0[i] + b2r[0]));
            h2b[row * HPITCH + n0 + 16 + ln] = (short)f2bf(fast_tanh(acc1[i] + b2r[1]));
        }
        __syncthreads();

        // ---- layer 3 + Euler update (waves 0..3): out = h2 @ W3 + b3 ----
        if (w < 4) {
            v4f acc = {0.f, 0.f, 0.f, 0.f};
            #pragma unroll
            for (int ks = 0; ks < 8; ks++) {
                v8s a = *(const v8s*)(h2b + ln * HPITCH + 32 * ks + 8 * q);
                acc = __builtin_amdgcn_mfma_f32_16x16x32_bf16(a, w3f[ks], acc, 0, 0, 0);
            }
            #pragma unroll
            for (int i = 0; i < 4; i++) {
                int row = q * 4 + i;
                int col = 16 * w + ln;
                float xn = xs[row * STATE_DIM + col] + (acc[i] + b3r) * scale;
                xs[row * STATE_DIM + col] = xn;
                xb[row * XPITCH + col]    = (short)f2bf(xn);
            }
        }
        __syncthreads();
    }
}

extern "C" void kernel_launch(void* const* d_in, const int* in_sizes, int n_in,
                              void* d_out, int out_size, void* d_ws, size_t ws_size,
                              hipStream_t stream) {
    const float* x0 = (const float*)d_in[0];
    const float* W1 = (const float*)d_in[1];
    const float* b1 = (const float*)d_in[2];
    const float* W2 = (const float*)d_in[3];
    const float* b2 = (const float*)d_in[4];
    const float* W3 = (const float*)d_in[5];
    const float* b3 = (const float*)d_in[6];
    const float* dt = (const float*)d_in[7];
    const int* steps = (const int*)d_in[8];

    short* W1t = (short*)d_ws;            // 16384 bf16
    short* W2t = W1t + 64 * 256;          // 65536 bf16
    short* W3t = W2t + 256 * 256;         // 16384 bf16

    prep_weights<<<384, 256, 0, stream>>>(W1, W2, W3, W1t, W2t, W3t);
    ode_kernel<<<NBLK, 512, 0, stream>>>(x0, b1, b2, b3, dt, steps,
                                         W1t, W2t, W3t, (float*)d_out);
}